// Round 5
// baseline (463.780 us; speedup 1.0000x reference)
//
#include <hip/hip_runtime.h>
#include <math.h>

// Problem constants (fixed by reference setup_inputs):
//   stimuli: (16,16,304,608) fp32, eye: (16,16,6) fp32, out: (16,16,304,608) fp32
#define IMG_H 304
#define IMG_W 608
#define IMG_HW (IMG_H * IMG_W)   // 184832, divisible by 4
#define TPB 128                  // 2 waves; HW/(TPB*4) = 361 exactly

__global__ __launch_bounds__(TPB) void grid_sample_kernel(
    const float* __restrict__ stimuli,
    const float* __restrict__ eye,
    float* __restrict__ out)
{
    // Keep all implicit mul/add UNFUSED (hipcc device default is
    // -ffp-contract=fast-honor-pragmas). The only FMAs are the explicit
    // fmaf() calls modeling the einsum/dot accumulation chain.
    #pragma clang fp contract(off)

    const int bf = blockIdx.y;
    const float* __restrict__ img = stimuli + (size_t)bf * IMG_HW;
    float* __restrict__ o = out + (size_t)bf * IMG_HW;

    // Affine params (f32). Wave-uniform loads -> scalar broadcast.
    const float a0 = eye[bf * 6 + 0];
    const float a1 = eye[bf * 6 + 1];
    const float a2 = eye[bf * 6 + 2];
    const float a3 = eye[bf * 6 + 3];
    const float a4 = eye[bf * 6 + 4];
    const float a5 = eye[bf * 6 + 5];

    const int p = (blockIdx.x * TPB + threadIdx.x) * 4;  // flat pixel index, 4-aligned
    const int row = p / IMG_W;
    const int col = p - row * IMG_W;  // col % 4 == 0, col <= W-4 (no row crossing)

    // jnp.linspace(-1, 1, N, dtype=f32) semantics (modern JAX):
    //   t = iota(N-1)/(N-1)  (f32 division)
    //   out = start*(1-t) + stop*t  = fl(t - fl(1-t))   (start=-1, stop=1)
    //   endpoint appended exactly as `stop` (1.0f).
    float yg;
    if (row == IMG_H - 1) {
        yg = 1.0f;
    } else {
        const float t = (float)row / 303.0f;          // correctly-rounded f32 div
        yg = t - (1.0f - t);                          // unfused (contract off)
    }

    float res[4];
#pragma unroll
    for (int i = 0; i < 4; ++i) {
        const int j = col + i;
        float xg;
        if (j == IMG_W - 1) {
            xg = 1.0f;
        } else {
            const float t = (float)j / 607.0f;
            xg = t - (1.0f - t);
        }

        // einsum 'bfij,jp->bfip' as an f32 FMA accumulation chain over j:
        //   acc = rn(a0*xg); acc = fma(a1, yg, acc); acc = rn(acc + a2*1)
        const float xs = fmaf(a1, yg, a0 * xg) + a2;
        const float ys = fmaf(a4, yg, a3 * xg) + a5;

        // (x + 1.0) * W / 2.0 — separate f32 ops (unfused; div by 2 exact)
        const float x = ((xs + 1.0f) * (float)IMG_W) / 2.0f;
        const float y = ((ys + 1.0f) * (float)IMG_H) / 2.0f;

        const float fx0 = floorf(x);
        const float fy0 = floorf(y);
        int x0 = (int)fx0;
        int y0 = (int)fy0;
        int x1 = x0 + 1;
        int y1 = y0 + 1;
        x0 = min(max(x0, 0), IMG_W - 1);
        x1 = min(max(x1, 0), IMG_W - 1);
        y0 = min(max(y0, 0), IMG_H - 1);
        y1 = min(max(y1, 0), IMG_H - 1);

        const float x0f = (float)x0, x1f = (float)x1;
        const float y0f = (float)y0, y1f = (float)y1;

        const float Ia = img[y0 * IMG_W + x0];
        const float Ib = img[y1 * IMG_W + x0];
        const float Ic = img[y0 * IMG_W + x1];
        const float Id = img[y1 * IMG_W + x1];

        // elementwise f32 weight arithmetic, unfused
        const float wxa = x1f - x;
        const float wxb = x - x0f;
        const float wya = y1f - y;
        const float wyb = y - y0f;

        const float wa = wxa * wya;
        const float wb = wxa * wyb;
        const float wc = wxb * wya;
        const float wd = wxb * wyb;

        // ((wa*Ia + wb*Ib) + wc*Ic) + wd*Id, left-assoc, unfused
        const float s0 = (wa * Ia) + (wb * Ib);
        const float s1 = s0 + (wc * Ic);
        res[i] = s1 + (wd * Id);
    }

    float4 v = make_float4(res[0], res[1], res[2], res[3]);
    *reinterpret_cast<float4*>(o + p) = v;
}

extern "C" void kernel_launch(void* const* d_in, const int* in_sizes, int n_in,
                              void* d_out, int out_size, void* d_ws, size_t ws_size,
                              hipStream_t stream) {
    const float* stimuli = (const float*)d_in[0];
    const float* eye     = (const float*)d_in[1];
    float* out           = (float*)d_out;

    const int n_imgs = in_sizes[1] / 6;            // 256
    const int blocks_x = IMG_HW / (TPB * 4);       // 361
    dim3 grid(blocks_x, n_imgs);
    grid_sample_kernel<<<grid, TPB, 0, stream>>>(stimuli, eye, out);
}